// Round 5
// baseline (171.939 us; speedup 1.0000x reference)
//
#include <hip/hip_runtime.h>
#include <math.h>

#define BSZ   256
#define RANK  16
#define IN_D  784
#define H1D   512
#define OUT_D 10
#define TOTAL 29610
#define LDB 136         // padded LDS B row stride (bf16 elems)

// t-regions of the generated vector (per batch):
// [0,8192) A1 | [8192,20736) B1F | [20736,21248) bias1
// [21248,21408) A2 | [21408,29600) B2F | [29600,29610) bias2
// All B1F/B2F rank-row boundaries are multiples of 16 (784=49*16, 512=32*16),
// so each MFMA 16-col group lies within one rank row r -> epilogue contraction valid.

typedef __attribute__((ext_vector_type(8))) short short8;
typedef __attribute__((ext_vector_type(4))) short short4v;
typedef __attribute__((ext_vector_type(4))) float f32x4;

__device__ __forceinline__ short f2bf(float f) {      // RNE fp32 -> bf16
    unsigned u = __float_as_uint(f);
    unsigned r = (u + 0x7fffu + ((u >> 16) & 1u)) >> 16;
    return (short)r;
}
__device__ __forceinline__ float bf2f(short s) {
    return __uint_as_float(((unsigned)(unsigned short)s) << 16);
}

// ---------------- fused conv1+conv2 per batch: img -> h2 (256 x 1568); also zeros v1/v2 ----------------
__global__ __launch_bounds__(256) void front_k(
    const float* __restrict__ img, const float* __restrict__ c1w, const float* __restrict__ c1b,
    const float* __restrict__ c2w, const float* __restrict__ c2b,
    float* __restrict__ h2g, float* __restrict__ vzero /*8192 floats: v1|v2*/) {
    __shared__ float xs[784];
    __shared__ float w1s[144];
    __shared__ float b1s[16], b2s[32];
    __shared__ float h1p[16 * 14 * 16];   // [ic][iy][16]
    __shared__ float c2ws[32 * 144];      // native [oc][ic*9+t]
    int b = blockIdx.x, tid = threadIdx.x;
    if (tid < 32) vzero[blockIdx.x * 32 + tid] = 0.f;   // 256 blocks x 32 = 8192
    for (int i = tid; i < 196; i += 256) ((float4*)xs)[i] = ((const float4*)(img + b * 784))[i];
    for (int i = tid; i < 144; i += 256) w1s[i] = c1w[i];
    for (int i = tid; i < 1152; i += 256) ((float4*)c2ws)[i] = ((const float4*)c2w)[i];
    if (tid < 16) b1s[tid] = c1b[tid];
    if (tid < 32) b2s[tid] = c2b[tid];
    __syncthreads();
#pragma unroll 1
    for (int o = tid; o < 3136; o += 256) {
        int oc = o / 196, pos = o % 196, oy = pos / 14, ox = pos % 14;
        float acc = b1s[oc];
        const float* wb = &w1s[oc * 9];
#pragma unroll
        for (int ky = 0; ky < 3; ky++) {
            int iy = oy * 2 - 1 + ky;
            if ((unsigned)iy < 28u) {
#pragma unroll
                for (int kx = 0; kx < 3; kx++) {
                    int ix = ox * 2 - 1 + kx;
                    if ((unsigned)ix < 28u) acc += xs[iy * 28 + ix] * wb[ky * 3 + kx];
                }
            }
        }
        h1p[oc * 224 + oy * 16 + ox] = fmaxf(acc, 0.f);
    }
    __syncthreads();
    int oc = tid & 31, oy = tid >> 5;
    if (oy < 7) {
        float a7[7];
#pragma unroll
        for (int ox = 0; ox < 7; ox++) a7[ox] = b2s[oc];
#pragma unroll 1
        for (int ic = 0; ic < 16; ic++) {
            const float* wp = &c2ws[oc * 144 + ic * 9];
            float w[9];
#pragma unroll
            for (int t = 0; t < 9; t++) w[t] = wp[t];
#pragma unroll
            for (int ky = 0; ky < 3; ky++) {
                int iy = oy * 2 - 1 + ky;
                if ((unsigned)iy < 14u) {
                    const float4* rp = (const float4*)&h1p[ic * 224 + iy * 16];
                    float r[16];
#pragma unroll
                    for (int q = 0; q < 4; q++) {
                        float4 v = rp[q];
                        r[q * 4 + 0] = v.x; r[q * 4 + 1] = v.y;
                        r[q * 4 + 2] = v.z; r[q * 4 + 3] = v.w;
                    }
#pragma unroll
                    for (int ox = 0; ox < 7; ox++) {
#pragma unroll
                        for (int kx = 0; kx < 3; kx++) {
                            int ix = 2 * ox + kx - 1;
                            if (ix >= 0) a7[ox] += r[ix] * w[ky * 3 + kx];
                        }
                    }
                }
            }
        }
        float* dst = h2g + b * 1568 + oc * 49 + oy * 7;
#pragma unroll
        for (int ox = 0; ox < 7; ox++) dst[ox] = fmaxf(a7[ox], 0.f);
    }
}

// ---------------- style -> s128 -> bf16 hi/lo ----------------
__global__ __launch_bounds__(512) void style_k(
    const float* __restrict__ h2g, const float* __restrict__ sew, const float* __restrict__ seb,
    const float* __restrict__ g1w, const float* __restrict__ g1b,
    short* __restrict__ Shi, short* __restrict__ Slo) {
    __shared__ float h2l[1568];
    __shared__ float red[512];
    __shared__ float style[64];
    int b = blockIdx.x, tid = threadIdx.x;
    if (tid < 392) ((float4*)h2l)[tid] = ((const float4*)(h2g + b * 1568))[tid];
    __syncthreads();
    {
        int j = tid & 63, p = tid >> 6;
        const float4* wr = (const float4*)(sew + j * 1568) + p * 49;
        const float4* hr = (const float4*)h2l + p * 49;
        float acc = 0.f;
#pragma unroll 7
        for (int i = 0; i < 49; i++) {
            float4 w = wr[i], h = hr[i];
            acc += w.x * h.x + w.y * h.y + w.z * h.z + w.w * h.w;
        }
        red[p * 64 + j] = acc;
    }
    __syncthreads();
    if (tid < 64) {
        float a = seb[tid];
#pragma unroll
        for (int p = 0; p < 8; p++) a += red[p * 64 + tid];
        style[tid] = tanhf(a);
    }
    __syncthreads();
    if (tid < 128) {
        const float4* wr = (const float4*)(g1w + tid * 64);
        const float4* sv = (const float4*)style;
        float acc = g1b[tid];
#pragma unroll
        for (int q = 0; q < 16; q++) {
            float4 w = wr[q], s = sv[q];
            acc += w.x * s.x + w.y * s.y + w.z * s.z + w.w * s.w;
        }
        float v = fmaxf(acc, 0.f);
        short hi = f2bf(v);
        Shi[b * 128 + tid] = hi;
        Slo[b * 128 + tid] = f2bf(v - bf2f(hi));
    }
}

// ---- shared MFMA core macro'd via device function: stage B tile + compute acc[8] ----
__device__ __forceinline__ void stage_b(const float* __restrict__ g2w, int n0,
                                        short* Bhi, short* Blo, int tid) {
    int r = tid >> 2, h = tid & 3;
    int t = n0 + r;
    short* dhi = Bhi + r * LDB + h * 32;
    short* dlo = Blo + r * LDB + h * 32;
    if (t < TOTAL) {
        const float4* src = (const float4*)(g2w + (long)t * 128 + h * 32);
#pragma unroll
        for (int i = 0; i < 8; i++) {
            float4 wv = src[i];
            short4v ph, pl;
            ph.x = f2bf(wv.x); ph.y = f2bf(wv.y); ph.z = f2bf(wv.z); ph.w = f2bf(wv.w);
            pl.x = f2bf(wv.x - bf2f(ph.x)); pl.y = f2bf(wv.y - bf2f(ph.y));
            pl.z = f2bf(wv.z - bf2f(ph.z)); pl.w = f2bf(wv.w - bf2f(ph.w));
            *(short4v*)(dhi + i * 4) = ph;
            *(short4v*)(dlo + i * 4) = pl;
        }
    } else {
        short4v z = {0, 0, 0, 0};
#pragma unroll
        for (int i = 0; i < 8; i++) { *(short4v*)(dhi + i * 4) = z; *(short4v*)(dlo + i * 4) = z; }
    }
}

__device__ __forceinline__ void mfma_core(const short* __restrict__ Shi, const short* __restrict__ Slo,
                                          const short* Bhi, const short* Blo,
                                          int mrow, int col, int quad, f32x4 acc[8]) {
    short8 Ah[4], Al[4];
#pragma unroll
    for (int ks = 0; ks < 4; ks++) {
        Ah[ks] = *(const short8*)(Shi + mrow * 128 + ks * 32 + quad * 8);
        Al[ks] = *(const short8*)(Slo + mrow * 128 + ks * 32 + quad * 8);
    }
#pragma unroll
    for (int nt = 0; nt < 8; nt++) acc[nt] = (f32x4){0.f, 0.f, 0.f, 0.f};
#pragma unroll
    for (int nt = 0; nt < 8; nt++) {
#pragma unroll
        for (int ks = 0; ks < 4; ks++) {
            int bofs = (nt * 16 + col) * LDB + ks * 32 + quad * 8;
            short8 bh = *(const short8*)(Bhi + bofs);
            short8 bl = *(const short8*)(Blo + bofs);
            acc[nt] = __builtin_amdgcn_mfma_f32_16x16x32_bf16(Ah[ks], bh, acc[nt], 0, 0, 0);
            acc[nt] = __builtin_amdgcn_mfma_f32_16x16x32_bf16(Al[ks], bh, acc[nt], 0, 0, 0);
            acc[nt] = __builtin_amdgcn_mfma_f32_16x16x32_bf16(Ah[ks], bl, acc[nt], 0, 0, 0);
        }
    }
}

// ---------------- gemm1: t in [0, 21248): A1 store | B1F contract->v1 | bias1 store ----------------
// grid (166, 2), block 512. Region is block-uniform (boundaries 8192=64*128, 20736=162*128).
__global__ __launch_bounds__(512, 1) void gemm1_k(
    const short* __restrict__ Shi, const short* __restrict__ Slo,
    const float* __restrict__ g2w, const float* __restrict__ g2b,
    const float* __restrict__ images,
    float* __restrict__ a1buf, float* __restrict__ bias1buf, float* __restrict__ v1) {
    __shared__ short Bhi[128 * LDB];
    __shared__ short Blo[128 * LDB];
    int tid = threadIdx.x;
    int n0 = blockIdx.x * 128;
    int m0 = blockIdx.y * 128;
    stage_b(g2w, n0, Bhi, Blo, tid);
    __syncthreads();
    int lane = tid & 63, w = tid >> 6;
    int col = lane & 15, quad = lane >> 4;
    f32x4 acc[8];
    mfma_core(Shi, Slo, Bhi, Blo, m0 + w * 16 + col, col, quad, acc);
    int b0 = m0 + w * 16 + quad * 4;
    int bx = blockIdx.x;
    if (bx < 64) {                         // A1 region
#pragma unroll
        for (int nt = 0; nt < 8; nt++) {
            int tcol = n0 + nt * 16 + col;
            float bias = g2b[tcol];
#pragma unroll
            for (int j = 0; j < 4; j++)
                a1buf[(long)(b0 + j) * 8192 + tcol] = acc[nt][j] + bias;
        }
    } else if (bx < 162) {                 // B1F region: contract with x
#pragma unroll
        for (int nt = 0; nt < 8; nt++) {
            int tcol = n0 + nt * 16 + col;
            float bias = g2b[tcol];
            unsigned tloc = (unsigned)(tcol - 8192);
            unsigned r = tloc / 784u;
            unsigned i = tloc - r * 784u;
            float s[4];
#pragma unroll
            for (int j = 0; j < 4; j++)
                s[j] = (acc[nt][j] + bias) * images[(b0 + j) * 784 + i];
#pragma unroll
            for (int m = 1; m < 16; m <<= 1) {
#pragma unroll
                for (int j = 0; j < 4; j++) s[j] += __shfl_xor(s[j], m, 64);
            }
            if (col == 0) {
#pragma unroll
                for (int j = 0; j < 4; j++) atomicAdd(&v1[(b0 + j) * 16 + r], s[j]);
            }
        }
    } else {                               // bias1 region
#pragma unroll
        for (int nt = 0; nt < 8; nt++) {
            int tcol = n0 + nt * 16 + col;
            float bias = g2b[tcol];
            int o = tcol - 20736;
#pragma unroll
            for (int j = 0; j < 4; j++)
                bias1buf[(b0 + j) * 512 + o] = acc[nt][j] + bias;
        }
    }
}

// ---------------- h1[b,o] = relu(bias1 + A1[o,:].v1) ----------------
__global__ __launch_bounds__(512) void h1_k(
    const float* __restrict__ a1buf, const float* __restrict__ bias1buf,
    const float* __restrict__ v1, float* __restrict__ h1f) {
    __shared__ float v1s[16];
    int b = blockIdx.x, o = threadIdx.x;
    if (o < 16) v1s[o] = v1[b * 16 + o];
    __syncthreads();
    const float4* row = (const float4*)(a1buf + (long)b * 8192 + o * 16);
    const float4* v4 = (const float4*)v1s;
    float acc = bias1buf[b * 512 + o];
#pragma unroll
    for (int q = 0; q < 4; q++) {
        float4 a = row[q], v = v4[q];
        acc += a.x * v.x + a.y * v.y + a.z * v.z + a.w * v.w;
    }
    h1f[b * 512 + o] = fmaxf(acc, 0.f);
}

// ---------------- gemm2: t in [21248, 29616): A2 store | B2F contract->v2 | bias2 store ----------------
// grid (66, 2). Region per 16-col group (boundaries 21408, 29600 are 16-multiples).
__global__ __launch_bounds__(512, 1) void gemm2_k(
    const short* __restrict__ Shi, const short* __restrict__ Slo,
    const float* __restrict__ g2w, const float* __restrict__ g2b,
    const float* __restrict__ h1f,
    float* __restrict__ a2buf, float* __restrict__ bias2buf, float* __restrict__ v2) {
    __shared__ short Bhi[128 * LDB];
    __shared__ short Blo[128 * LDB];
    int tid = threadIdx.x;
    int n0 = 21248 + blockIdx.x * 128;
    int m0 = blockIdx.y * 128;
    stage_b(g2w, n0, Bhi, Blo, tid);
    __syncthreads();
    int lane = tid & 63, w = tid >> 6;
    int col = lane & 15, quad = lane >> 4;
    f32x4 acc[8];
    mfma_core(Shi, Slo, Bhi, Blo, m0 + w * 16 + col, col, quad, acc);
    int b0 = m0 + w * 16 + quad * 4;
#pragma unroll
    for (int nt = 0; nt < 8; nt++) {
        int tg = n0 + nt * 16;
        int tcol = tg + col;
        if (tg < 21408) {                  // A2
            float bias = g2b[tcol];
#pragma unroll
            for (int j = 0; j < 4; j++)
                a2buf[(b0 + j) * 160 + (tcol - 21248)] = acc[nt][j] + bias;
        } else if (tg < 29600) {           // B2F: contract with h1
            float bias = g2b[tcol];
            unsigned tloc = (unsigned)(tcol - 21408);
            unsigned r = tloc >> 9;
            unsigned i = tloc & 511u;
            float s[4];
#pragma unroll
            for (int j = 0; j < 4; j++)
                s[j] = (acc[nt][j] + bias) * h1f[(b0 + j) * 512 + i];
#pragma unroll
            for (int m = 1; m < 16; m <<= 1) {
#pragma unroll
                for (int j = 0; j < 4; j++) s[j] += __shfl_xor(s[j], m, 64);
            }
            if (col == 0) {
#pragma unroll
                for (int j = 0; j < 4; j++) atomicAdd(&v2[(b0 + j) * 16 + r], s[j]);
            }
        } else {                           // bias2 (t in [29600,29610)) else dead
            if (tcol < 29610) {
                float bias = g2b[tcol];
#pragma unroll
                for (int j = 0; j < 4; j++)
                    bias2buf[(b0 + j) * 16 + (tcol - 29600)] = acc[nt][j] + bias;
            }
        }
    }
}

// ---------------- out[b,o] = bias2 + A2[o,:].v2 ----------------
__global__ __launch_bounds__(64) void out_k(
    const float* __restrict__ a2buf, const float* __restrict__ bias2buf,
    const float* __restrict__ v2, float* __restrict__ out) {
    __shared__ float v2s[16];
    int b = blockIdx.x, tid = threadIdx.x;
    if (tid < 16) v2s[tid] = v2[b * 16 + tid];
    __syncthreads();
    if (tid < OUT_D) {
        const float* row = a2buf + b * 160 + tid * 16;
        float acc = bias2buf[b * 16 + tid];
#pragma unroll
        for (int r = 0; r < 16; r++) acc += row[r] * v2s[r];
        out[b * OUT_D + tid] = acc;
    }
}

extern "C" void kernel_launch(void* const* d_in, const int* in_sizes, int n_in,
                              void* d_out, int out_size, void* d_ws, size_t ws_size,
                              hipStream_t stream) {
    const float* images = (const float*)d_in[0];
    const float* c1w = (const float*)d_in[1];
    const float* c1b = (const float*)d_in[2];
    const float* c2w = (const float*)d_in[3];
    const float* c2b = (const float*)d_in[4];
    const float* sew = (const float*)d_in[5];
    const float* seb = (const float*)d_in[6];
    const float* g1w = (const float*)d_in[7];
    const float* g1b = (const float*)d_in[8];
    const float* g2w = (const float*)d_in[9];
    const float* g2b = (const float*)d_in[10];
    float* out = (float*)d_out;

    float* ws = (float*)d_ws;
    float* h2g      = ws;                    // 401408
    float* v1       = h2g + 401408;          // 4096
    float* v2       = v1 + 4096;             // 4096  (v1|v2 contiguous: front_k zeros both)
    float* a1buf    = v2 + 4096;             // 2097152
    float* bias1buf = a1buf + 2097152;       // 131072
    float* a2buf    = bias1buf + 131072;     // 40960
    float* bias2buf = a2buf + 40960;         // 4096
    float* h1f      = bias2buf + 4096;       // 131072
    short* Shi      = (short*)(h1f + 131072);// 32768 shorts
    short* Slo      = Shi + 32768;           // 32768 shorts   total ~11.3 MB

    front_k<<<dim3(BSZ), dim3(256), 0, stream>>>(images, c1w, c1b, c2w, c2b, h2g, v1);
    style_k<<<dim3(BSZ), dim3(512), 0, stream>>>(h2g, sew, seb, g1w, g1b, Shi, Slo);
    gemm1_k<<<dim3(166, 2), dim3(512), 0, stream>>>(Shi, Slo, g2w, g2b, images, a1buf, bias1buf, v1);
    h1_k<<<dim3(BSZ), dim3(512), 0, stream>>>(a1buf, bias1buf, v1, h1f);
    gemm2_k<<<dim3(66, 2), dim3(512), 0, stream>>>(Shi, Slo, g2w, g2b, h1f, a2buf, bias2buf, v2);
    out_k<<<dim3(BSZ), dim3(64), 0, stream>>>(a2buf, bias2buf, v2, out);
}

// Round 6
// 140.021 us; speedup vs baseline: 1.2279x; 1.2279x over previous
//
#include <hip/hip_runtime.h>
#include <math.h>

#define BSZ   256
#define RANK  16
#define IN_D  784
#define H1D   512
#define OUT_D 10
#define TOTAL 29610
#define GSTRIDE 29616   // padded g row stride (16B-aligned rows)
#define LDB 132         // LDS B row stride in shorts: start-bank 2*col+4*quad -> uniform 8/bank
                        // (136 put all 64 lanes on 4 start banks -> half banks idle)

// g layout offsets (per batch row)
#define OFF_A1    0
#define OFF_B1F   8192
#define OFF_BIAS1 20736
#define OFF_A2    21248
#define OFF_B2F   21408
#define OFF_BIAS2 29600

typedef __attribute__((ext_vector_type(8))) short short8;
typedef __attribute__((ext_vector_type(4))) short short4v;
typedef __attribute__((ext_vector_type(4))) float f32x4;

__device__ __forceinline__ short f2bf(float f) {      // RNE fp32 -> bf16
    unsigned u = __float_as_uint(f);
    unsigned r = (u + 0x7fffu + ((u >> 16) & 1u)) >> 16;
    return (short)r;
}
__device__ __forceinline__ float bf2f(short s) {
    return __uint_as_float(((unsigned)(unsigned short)s) << 16);
}

// ---------------- fused conv1+conv2+style per batch: img -> Shi/Slo ----------------
__global__ __launch_bounds__(256) void front_style_k(
    const float* __restrict__ img, const float* __restrict__ c1w, const float* __restrict__ c1b,
    const float* __restrict__ c2w, const float* __restrict__ c2b,
    const float* __restrict__ sew, const float* __restrict__ seb,
    const float* __restrict__ g1w, const float* __restrict__ g1b,
    short* __restrict__ Shi, short* __restrict__ Slo) {
    __shared__ float xs[784];
    __shared__ float w1s[144];
    __shared__ float b1s[16], b2s[32];
    __shared__ float h1p[16 * 14 * 16];   // [ic][iy][16]
    __shared__ float c2ws[32 * 144];      // native [oc][ic*9+t]
    __shared__ float h2l[1568];
    __shared__ float red[256];
    __shared__ float style[64];
    int b = blockIdx.x, tid = threadIdx.x;
    for (int i = tid; i < 196; i += 256) ((float4*)xs)[i] = ((const float4*)(img + b * 784))[i];
    for (int i = tid; i < 144; i += 256) w1s[i] = c1w[i];
    for (int i = tid; i < 1152; i += 256) ((float4*)c2ws)[i] = ((const float4*)c2w)[i];
    if (tid < 16) b1s[tid] = c1b[tid];
    if (tid < 32) b2s[tid] = c2b[tid];
    __syncthreads();
    // conv1: 16 oc x 14x14, stride 2 pad 1
#pragma unroll 1
    for (int o = tid; o < 3136; o += 256) {
        int oc = o / 196, pos = o % 196, oy = pos / 14, ox = pos % 14;
        float acc = b1s[oc];
        const float* wb = &w1s[oc * 9];
#pragma unroll
        for (int ky = 0; ky < 3; ky++) {
            int iy = oy * 2 - 1 + ky;
            if ((unsigned)iy < 28u) {
#pragma unroll
                for (int kx = 0; kx < 3; kx++) {
                    int ix = ox * 2 - 1 + kx;
                    if ((unsigned)ix < 28u) acc += xs[iy * 28 + ix] * wb[ky * 3 + kx];
                }
            }
        }
        h1p[oc * 224 + oy * 16 + ox] = fmaxf(acc, 0.f);
    }
    __syncthreads();
    // conv2: 32 oc x 7x7 -> h2l (LDS, never to global)
    {
        int oc = tid & 31, oy = tid >> 5;
        if (oy < 7) {
            float a7[7];
#pragma unroll
            for (int ox = 0; ox < 7; ox++) a7[ox] = b2s[oc];
#pragma unroll 1
            for (int ic = 0; ic < 16; ic++) {
                const float* wp = &c2ws[oc * 144 + ic * 9];
                float w[9];
#pragma unroll
                for (int t = 0; t < 9; t++) w[t] = wp[t];
#pragma unroll
                for (int ky = 0; ky < 3; ky++) {
                    int iy = oy * 2 - 1 + ky;
                    if ((unsigned)iy < 14u) {
                        const float4* rp = (const float4*)&h1p[ic * 224 + iy * 16];
                        float r[16];
#pragma unroll
                        for (int q = 0; q < 4; q++) {
                            float4 v = rp[q];
                            r[q * 4 + 0] = v.x; r[q * 4 + 1] = v.y;
                            r[q * 4 + 2] = v.z; r[q * 4 + 3] = v.w;
                        }
#pragma unroll
                        for (int ox = 0; ox < 7; ox++) {
#pragma unroll
                            for (int kx = 0; kx < 3; kx++) {
                                int ix = 2 * ox + kx - 1;
                                if (ix >= 0) a7[ox] += r[ix] * w[ky * 3 + kx];
                            }
                        }
                    }
                }
            }
            float* dst = h2l + oc * 49 + oy * 7;
#pragma unroll
            for (int ox = 0; ox < 7; ox++) dst[ox] = fmaxf(a7[ox], 0.f);
        }
    }
    __syncthreads();
    // style = tanh(h2 @ sew.T + seb): 64 outputs x 4 K-partials (98 float4 each)
    {
        int j = tid & 63, p = tid >> 6;
        const float4* wr = (const float4*)(sew + j * 1568) + p * 98;
        const float4* hr = (const float4*)h2l + p * 98;
        float a0 = 0.f, a1 = 0.f;
#pragma unroll 2
        for (int i = 0; i < 98; i += 2) {
            float4 w = wr[i], h = hr[i];
            a0 += w.x * h.x + w.y * h.y + w.z * h.z + w.w * h.w;
            float4 w2 = wr[i + 1], h2 = hr[i + 1];
            a1 += w2.x * h2.x + w2.y * h2.y + w2.z * h2.z + w2.w * h2.w;
        }
        red[p * 64 + j] = a0 + a1;
    }
    __syncthreads();
    if (tid < 64) {
        float a = seb[tid] + red[tid] + red[64 + tid] + red[128 + tid] + red[192 + tid];
        style[tid] = tanhf(a);
    }
    __syncthreads();
    // s128 = relu(style @ g1w.T + g1b) -> bf16 hi/lo split
    if (tid < 128) {
        const float4* wr = (const float4*)(g1w + tid * 64);
        const float4* sv = (const float4*)style;
        float acc = g1b[tid];
#pragma unroll
        for (int q = 0; q < 16; q++) {
            float4 w = wr[q], s = sv[q];
            acc += w.x * s.x + w.y * s.y + w.z * s.z + w.w * s.w;
        }
        float v = fmaxf(acc, 0.f);
        short hi = f2bf(v);
        Shi[b * 128 + tid] = hi;
        Slo[b * 128 + tid] = f2bf(v - bf2f(hi));
    }
}

// ---------------- g[b][t] = S[b,:128].W[t,:128] + g2b[t], bf16x3 MFMA ----------------
// grid 232 (1D), block 512 (8 waves). Single pass: M=256 all batches, each wave 2 m-tiles.
// W tile staged+converted ONCE per N-tile (r4 did it twice via gridDim.y=2).
__global__ __launch_bounds__(512, 1) void gemm_k(
    const short* __restrict__ Shi, const short* __restrict__ Slo,
    const float* __restrict__ g2w, const float* __restrict__ g2b,
    float* __restrict__ g) {
    __shared__ short Bhi[128 * LDB];
    __shared__ short Blo[128 * LDB];
    int tid = threadIdx.x;
    int n0 = blockIdx.x * 128;
    // stage + split B tile: 4 threads per row, 32 floats each
    {
        int r = tid >> 2, h = tid & 3;
        int t = n0 + r;
        short* dhi = Bhi + r * LDB + h * 32;
        short* dlo = Blo + r * LDB + h * 32;
        if (t < TOTAL) {
            const float4* src = (const float4*)(g2w + (long)t * 128 + h * 32);
#pragma unroll
            for (int i = 0; i < 8; i++) {
                float4 wv = src[i];
                short4v ph, pl;
                ph.x = f2bf(wv.x); ph.y = f2bf(wv.y); ph.z = f2bf(wv.z); ph.w = f2bf(wv.w);
                pl.x = f2bf(wv.x - bf2f(ph.x)); pl.y = f2bf(wv.y - bf2f(ph.y));
                pl.z = f2bf(wv.z - bf2f(ph.z)); pl.w = f2bf(wv.w - bf2f(ph.w));
                *(short4v*)(dhi + i * 4) = ph;
                *(short4v*)(dlo + i * 4) = pl;
            }
        } else {
            short4v z = {0, 0, 0, 0};
#pragma unroll
            for (int i = 0; i < 8; i++) { *(short4v*)(dhi + i * 4) = z; *(short4v*)(dlo + i * 4) = z; }
        }
    }
    __syncthreads();
    int lane = tid & 63, w = tid >> 6;
    int col = lane & 15, quad = lane >> 4;
    // A fragments for 2 m-tiles: A[m = lane&15][k = quad*8+j]
    short8 Ah[2][4], Al[2][4];
#pragma unroll
    for (int mt = 0; mt < 2; mt++) {
        int mrow = w * 32 + mt * 16 + col;
#pragma unroll
        for (int ks = 0; ks < 4; ks++) {
            Ah[mt][ks] = *(const short8*)(Shi + mrow * 128 + ks * 32 + quad * 8);
            Al[mt][ks] = *(const short8*)(Slo + mrow * 128 + ks * 32 + quad * 8);
        }
    }
    f32x4 acc[2][8];
#pragma unroll
    for (int mt = 0; mt < 2; mt++)
#pragma unroll
        for (int nt = 0; nt < 8; nt++) acc[mt][nt] = (f32x4){0.f, 0.f, 0.f, 0.f};
#pragma unroll
    for (int nt = 0; nt < 8; nt++) {
#pragma unroll
        for (int ks = 0; ks < 4; ks++) {
            int bofs = (nt * 16 + col) * LDB + ks * 32 + quad * 8;
            short8 bh = *(const short8*)(Bhi + bofs);
            short8 bl = *(const short8*)(Blo + bofs);
#pragma unroll
            for (int mt = 0; mt < 2; mt++) {
                acc[mt][nt] = __builtin_amdgcn_mfma_f32_16x16x32_bf16(Ah[mt][ks], bh, acc[mt][nt], 0, 0, 0);
                acc[mt][nt] = __builtin_amdgcn_mfma_f32_16x16x32_bf16(Al[mt][ks], bh, acc[mt][nt], 0, 0, 0);
                acc[mt][nt] = __builtin_amdgcn_mfma_f32_16x16x32_bf16(Ah[mt][ks], bl, acc[mt][nt], 0, 0, 0);
            }
        }
    }
    // epilogue: C col = lane&15 (t), row = quad*4 + j (batch)
#pragma unroll
    for (int nt = 0; nt < 8; nt++) {
        int tcol = n0 + nt * 16 + col;
        if (tcol < TOTAL) {
            float bias = g2b[tcol];
#pragma unroll
            for (int mt = 0; mt < 2; mt++) {
                int rbase = w * 32 + mt * 16 + quad * 4;
#pragma unroll
                for (int j = 0; j < 4; j++)
                    g[(long)(rbase + j) * GSTRIDE + tcol] = acc[mt][nt][j] + bias;
            }
        }
    }
}

// ---------------- per-batch low-rank apply (512 threads/block) ----------------
__global__ __launch_bounds__(512) void apply_k(const float* __restrict__ img,
                        const float* __restrict__ g, float* __restrict__ out) {
    __shared__ float x[IN_D];
    __shared__ float red[512];
    __shared__ float v1[RANK];
    __shared__ float h1s[H1D];
    __shared__ float v2[RANK];
    int b = blockIdx.x, tid = threadIdx.x;
    const float* gb = g + (long)b * GSTRIDE;
    {
        const float4* src = (const float4*)(img + b * IN_D);
        float4* dst = (float4*)x;
        if (tid < 196) dst[tid] = src[tid];
    }
    __syncthreads();
    {
        int r = tid >> 5, p = tid & 31;
        const float4* row = (const float4*)(gb + OFF_B1F + r * IN_D);
        const float4* x4 = (const float4*)x;
        float acc = 0.f;
        for (int i = p; i < 196; i += 32) {
            float4 w = row[i], xv = x4[i];
            acc += w.x * xv.x + w.y * xv.y + w.z * xv.z + w.w * xv.w;
        }
        red[tid] = acc;
    }
    __syncthreads();
    if (tid < 16) {
        float s = 0.f;
#pragma unroll
        for (int p = 0; p < 32; p++) s += red[tid * 32 + p];
        v1[tid] = s;
    }
    __syncthreads();
    {
        const float4* row = (const float4*)(gb + OFF_A1 + tid * RANK);
        float acc = gb[OFF_BIAS1 + tid];
        const float4* v14 = (const float4*)v1;
#pragma unroll
        for (int q = 0; q < 4; q++) {
            float4 a = row[q], v = v14[q];
            acc += a.x * v.x + a.y * v.y + a.z * v.z + a.w * v.w;
        }
        h1s[tid] = fmaxf(acc, 0.f);
    }
    __syncthreads();
    {
        int r = tid >> 5, p = tid & 31;
        const float4* row = (const float4*)(gb + OFF_B2F + r * H1D);
        const float4* h4 = (const float4*)h1s;
        float acc = 0.f;
        for (int i = p; i < 128; i += 32) {
            float4 w = row[i], hv = h4[i];
            acc += w.x * hv.x + w.y * hv.y + w.z * hv.z + w.w * hv.w;
        }
        red[tid] = acc;
    }
    __syncthreads();
    if (tid < 16) {
        float s = 0.f;
#pragma unroll
        for (int p = 0; p < 32; p++) s += red[tid * 32 + p];
        v2[tid] = s;
    }
    __syncthreads();
    if (tid < OUT_D) {
        const float* row = gb + OFF_A2 + tid * RANK;
        float acc = gb[OFF_BIAS2 + tid];
#pragma unroll
        for (int r = 0; r < RANK; r++) acc += row[r] * v2[r];
        out[b * OUT_D + tid] = acc;
    }
}

extern "C" void kernel_launch(void* const* d_in, const int* in_sizes, int n_in,
                              void* d_out, int out_size, void* d_ws, size_t ws_size,
                              hipStream_t stream) {
    const float* images = (const float*)d_in[0];
    const float* c1w = (const float*)d_in[1];
    const float* c1b = (const float*)d_in[2];
    const float* c2w = (const float*)d_in[3];
    const float* c2b = (const float*)d_in[4];
    const float* sew = (const float*)d_in[5];
    const float* seb = (const float*)d_in[6];
    const float* g1w = (const float*)d_in[7];
    const float* g1b = (const float*)d_in[8];
    const float* g2w = (const float*)d_in[9];
    const float* g2b = (const float*)d_in[10];
    float* out = (float*)d_out;

    float* ws = (float*)d_ws;
    short* Shi = (short*)ws;                 // 32768 shorts
    short* Slo = Shi + 32768;                // 32768 shorts
    float* g   = ws + 32768;                 // 256*29616 floats (~30.3 MB)

    front_style_k<<<dim3(BSZ), dim3(256), 0, stream>>>(images, c1w, c1b, c2w, c2b,
                                                       sew, seb, g1w, g1b, Shi, Slo);
    gemm_k<<<dim3(232), dim3(512), 0, stream>>>(Shi, Slo, g2w, g2b, g);
    apply_k<<<dim3(BSZ), dim3(512), 0, stream>>>(images, g, out);
}